// Round 9
// baseline (29.055 us; speedup 1.0000x reference)
//
#include <hip/hip_runtime.h>
#include <cstdint>

#define NTYPES 39
#define NA 64
#define TABN (NTYPES*NTYPES)   // 1521
#define TABPAD 1536            // float4-aligned table extent in ws / LDS
#define MPB 4                  // molecules per block

typedef float float4v __attribute__((ext_vector_type(4)));
typedef int   int4v   __attribute__((ext_vector_type(4)));

// ---- kernel A: fill type-pair table + bond-weight table into workspace ----
__global__ __launch_bounds__(256) void table_kernel(
    const float* __restrict__ e,
    const float* __restrict__ alpha,
    const float* __restrict__ beta_p,
    float* __restrict__ ws)
{
  const int k = blockIdx.x * 256 + threadIdx.x;
  if (k < TABN){
    int a = k / NTYPES;
    int b = k - a*NTYPES;
    float d = e[b] - e[a];
    float t = powf(fabsf(d), beta_p[0]);
    ws[k] = (d > 0.f) ? t : ((d < 0.f) ? -t : 0.f);
  } else if (k < TABPAD){
    ws[k] = 0.f;
  } else if (k < TABPAD + 8){
    int q = k - TABPAD;
    float a0 = alpha[0], a1 = alpha[1], a2 = alpha[2], a3 = alpha[3];
    int af = q & 3;
    float bv = (af == 1) ? a0 : ((af == 2) ? a1 : ((af == 3) ? a2 : 0.f));
    if ((q & 4) && af != 0) bv += a3;    // marom needs Af>0 and both aromatic
    ws[k] = bv;
  }
}

// ---- kernel B: 4 molecules per block ----
__global__ __launch_bounds__(256) void vcharge_kernel(
    const int*   __restrict__ atoms,
    const float* __restrict__ A,
    const float* __restrict__ Q,
    const float* __restrict__ s,
    const float* __restrict__ alpha,
    const float* __restrict__ ws,
    float*       __restrict__ out,
    int B)
{
  __shared__ float    tab[TABPAD];         // signed |e_b - e_a|^beta by (a,b)
  __shared__ float    bw2[8];              // bond weight by (af | aromboth<<2)
  __shared__ uint32_t PRT[4*68];           // 2-bit cols, transposed [word][row]
  __shared__ unsigned long long MK[NA];    // 64-bit Af-nonzero row masks
  __shared__ float    EI[4*NA];            // per-wave partial e_i

  const int tid  = threadIdx.x;
  const int wid  = tid >> 6;
  const int lane = tid & 63;

  // ---- per-block setup: table copy (amortized over MPB molecules) ----
  {
    const float4v* w4 = (const float4v*)ws;
    float4v* t4 = (float4v*)tab;
    t4[tid] = w4[tid];
    if (tid < TABPAD/4 - 256) t4[256 + tid] = w4[256 + tid];
    if (tid < 8) bw2[tid] = ws[TABPAD + tid];
  }
  const float alpha4 = alpha[4];
  const uint64_t AROM = (1ull<<6)|(1ull<<10)|(1ull<<19)|(1ull<<20)|(1ull<<21)|(1ull<<22)|(1ull<<32);

  // molecule-invariant addressing
  const int sh    = 2 * (lane & 15);
  const int ibase = wid * 16;
  const uint32_t* rp_addr = &PRT[wid*68 + lane];
  const int4v*    cb      = (const int4v*)&PRT[(lane >> 4)*68 + wid*16];

  for (int mi = 0; mi < MPB; ++mi){
    const int m = blockIdx.x * MPB + mi;
    const bool act = (m < B);

    int ty = 0; float sinv = 1.f; int aromt = 0;
    unsigned long long aromBits = 0;
    if (act){
      // ---- phase 1: load 16KB matrix, quantize (Horner, exact), transpose ----
      const float4v* A4 = (const float4v*)(A + (size_t)m * (NA*NA));
      float4v v0 = A4[tid*4 + 0];
      float4v v1 = A4[tid*4 + 1];
      float4v v2 = A4[tid*4 + 2];
      float4v v3 = A4[tid*4 + 3];
      float flo = v1[3];
      flo = fmaf(flo, 4.f, v1[2]); flo = fmaf(flo, 4.f, v1[1]);
      flo = fmaf(flo, 4.f, v1[0]); flo = fmaf(flo, 4.f, v0[3]);
      flo = fmaf(flo, 4.f, v0[2]); flo = fmaf(flo, 4.f, v0[1]);
      flo = fmaf(flo, 4.f, v0[0]);
      float fhi = v3[3];
      fhi = fmaf(fhi, 4.f, v3[2]); fhi = fmaf(fhi, 4.f, v3[1]);
      fhi = fmaf(fhi, 4.f, v3[0]); fhi = fmaf(fhi, 4.f, v2[3]);
      fhi = fmaf(fhi, 4.f, v2[2]); fhi = fmaf(fhi, 4.f, v2[1]);
      fhi = fmaf(fhi, 4.f, v2[0]);
      uint32_t pk = (uint32_t)flo | ((uint32_t)fhi << 16);
      PRT[(tid & 3)*68 + (tid >> 2)] = pk;   // transposed: [word][row]

      ty   = atoms[m*NA + lane];
      sinv = 1.0f / s[ty];
      aromt = (int)((AROM >> ty) & 1ull);
    }
    aromBits = __ballot(aromt);              // identical per wave (inactive m: 0)
    const int aromsel = aromt << 2;

    __syncthreads();   // PRT (and on mi=0, tab/bw2) ready

    float ei = 0.f;
    float tv[16];
    unsigned long long mymk = 0;
    if (act){
      // ---- pass A: af + ballot row masks + bond-term FMA + tab stash ----
      const uint32_t rpw = *rp_addr;                 // A[lane][16w..16w+16)
      #pragma unroll
      for (int c = 0; c < 4; ++c){
        int4v cw = cb[c];                            // conflict-free b128
        #pragma unroll
        for (int q = 0; q < 4; ++q){
          const int k = c*4 + q;
          uint32_t w   = (uint32_t)cw[q];            // PRT[lane>>4][16w+k]
          uint32_t aij = (w >> sh) & 3u;             // A[i][lane]
          uint32_t aji = (rpw >> (2*k)) & 3u;        // A[lane][i]
          uint32_t af  = aij | aji;                  // Af[i][lane]
          unsigned long long bal = __ballot(af != 0u);
          mymk = (lane == k) ? bal : mymk;
          int arom_i = (int)((aromBits >> (ibase + k)) & 1ull);  // uniform
          int idx = (int)af + (aromsel & (0 - arom_i));
          float bw = bw2[idx];
          int tyi = __builtin_amdgcn_readlane(ty, ibase + k);    // uniform
          float t  = tab[tyi*NTYPES + ty];
          tv[k] = t;
          ei = fmaf(bw, t, ei);
        }
      }
      if (lane < 16) MK[ibase + lane] = mymk;
    }
    __syncthreads();   // MK ready

    if (act){
      // ---- pass B: one3 term via b64 preload + readlane (no per-k LDS) ----
      const unsigned long long mkj = MK[lane];               // own row mask
      const unsigned long long mkv = MK[ibase + (lane & 15)];// wave's 16 masks
      const int vlo = (int)(uint32_t)mkv;
      const int vhi = (int)(uint32_t)(mkv >> 32);
      #pragma unroll
      for (int k = 0; k < 16; ++k){
        uint32_t milo = (uint32_t)__builtin_amdgcn_readlane(vlo, k);
        uint32_t mihi = (uint32_t)__builtin_amdgcn_readlane(vhi, k);
        unsigned long long mki =
            (((unsigned long long)mihi) << 32) | milo;       // MK[ibase+k]
        float add = ((mki & mkj) != 0ull) ? alpha4 : 0.f;
        ei = fmaf(add, tv[k], ei);
      }
      EI[wid*NA + lane] = ei;
    }
    __syncthreads();   // EI ready; also fences MK/PRT reuse next iteration

    if (act && wid == 0){
      float eif = EI[lane] + EI[NA + lane] + EI[2*NA + lane] + EI[3*NA + lane];
      float esv = eif * sinv;
      float sv  = sinv;
      #pragma unroll
      for (int off = 32; off; off >>= 1){
        esv += __shfl_xor(esv, off);
        sv  += __shfl_xor(sv,  off);
      }
      const float lam = (Q[m] + esv) / sv;
      out[(size_t)m*NA + lane] = sinv * (lam - eif);
    }
  }
}

extern "C" void kernel_launch(void* const* d_in, const int* in_sizes, int n_in,
                              void* d_out, int out_size, void* d_ws, size_t ws_size,
                              hipStream_t stream)
{
  const int*   atoms = (const int*)  d_in[0];
  const float* A     = (const float*)d_in[1];
  const float* Q     = (const float*)d_in[2];
  const float* e     = (const float*)d_in[3];
  const float* s     = (const float*)d_in[4];
  const float* alpha = (const float*)d_in[5];
  const float* beta  = (const float*)d_in[6];
  float* out = (float*)d_out;
  float* ws  = (float*)d_ws;   // TABPAD+8 floats used

  const int B = in_sizes[2];                 // Q: one entry per molecule
  const int grid = (B + MPB - 1) / MPB;
  hipLaunchKernelGGL(table_kernel, dim3((TABPAD + 8 + 255)/256), dim3(256), 0, stream,
                     e, alpha, beta, ws);
  hipLaunchKernelGGL(vcharge_kernel, dim3(grid), dim3(256), 0, stream,
                     atoms, A, Q, s, alpha, ws, out, B);
}

// Round 11
// 27.228 us; speedup vs baseline: 1.0671x; 1.0671x over previous
//
#include <hip/hip_runtime.h>
#include <cstdint>

#define NTYPES 39
#define NA 64

typedef float float4v __attribute__((ext_vector_type(4)));
typedef int   int4v   __attribute__((ext_vector_type(4)));

__global__ __launch_bounds__(256) void vcharge_kernel(
    const int*   __restrict__ atoms,
    const float* __restrict__ A,
    const float* __restrict__ Q,
    const float* __restrict__ e,
    const float* __restrict__ s,
    const float* __restrict__ alpha,
    const float* __restrict__ beta_p,
    float*       __restrict__ out)
{
  __shared__ float    bw2[8];              // bond weight by (af | aromboth<<2)
  __shared__ uint32_t PRT[4*68];           // 2-bit cols, transposed [word][row]
  __shared__ unsigned long long MK[NA];    // 64-bit Af-nonzero row masks
  __shared__ float    EI[4*NA];            // per-wave partial e_i

  const int tid  = threadIdx.x;
  const int wid  = tid >> 6;
  const int lane = tid & 63;
  const int m    = blockIdx.x;

  if (tid < 8){
    float a0 = alpha[0], a1 = alpha[1], a2 = alpha[2], a3 = alpha[3];
    int af = tid & 3;
    float bv = (af == 1) ? a0 : ((af == 2) ? a1 : ((af == 3) ? a2 : 0.f));
    if ((tid & 4) && af != 0) bv += a3;   // marom needs Af>0 and both aromatic
    bw2[tid] = bv;
  }

  // ---- phase 1: load 16KB matrix, quantize via exact float Horner, transpose ----
  // thread t: row r = t>>2, cols [16*(t&3), +16)
  {
    const float4v* A4 = (const float4v*)(A + (size_t)m * (NA*NA));
    float4v v0 = A4[tid*4 + 0];
    float4v v1 = A4[tid*4 + 1];
    float4v v2 = A4[tid*4 + 2];
    float4v v3 = A4[tid*4 + 3];
    float flo = v1[3];
    flo = fmaf(flo, 4.f, v1[2]); flo = fmaf(flo, 4.f, v1[1]);
    flo = fmaf(flo, 4.f, v1[0]); flo = fmaf(flo, 4.f, v0[3]);
    flo = fmaf(flo, 4.f, v0[2]); flo = fmaf(flo, 4.f, v0[1]);
    flo = fmaf(flo, 4.f, v0[0]);
    float fhi = v3[3];
    fhi = fmaf(fhi, 4.f, v3[2]); fhi = fmaf(fhi, 4.f, v3[1]);
    fhi = fmaf(fhi, 4.f, v3[0]); fhi = fmaf(fhi, 4.f, v2[3]);
    fhi = fmaf(fhi, 4.f, v2[2]); fhi = fmaf(fhi, 4.f, v2[1]);
    fhi = fmaf(fhi, 4.f, v2[0]);
    uint32_t pk = (uint32_t)flo | ((uint32_t)fhi << 16);
    PRT[(tid & 3)*68 + (tid >> 2)] = pk;   // transposed: [word][row]
  }

  // per-lane atom constants (overlap with phase 1)
  const int ty = atoms[m*NA + lane];
  const float sinv = 1.0f / s[ty];
  const float ea   = e[ty];                // per-lane electronegativity
  const float beta = beta_p[0];
  const float alpha4 = alpha[4];
  const uint64_t AROM = (1ull<<6)|(1ull<<10)|(1ull<<19)|(1ull<<20)|(1ull<<21)|(1ull<<22)|(1ull<<32);
  const int aromt = (int)((AROM >> ty) & 1ull);
  const unsigned long long aromBits = __ballot(aromt);  // identical per wave
  const int aromsel = aromt << 2;

  __syncthreads();

  // ---- pass A (fused): af + ballot row masks + de_s on the fly + bond FMA ----
  const int sh  = 2 * (lane & 15);
  const uint32_t rpw = PRT[wid*68 + lane];        // A[lane][16w..16w+16)
  const int4v* cb = (const int4v*)&PRT[(lane >> 4)*68 + wid*16];
  const int ibase = wid * 16;
  float tv[16];                                   // stashed de_s values (VGPRs)
  float ei = 0.f;
  unsigned long long mymk = 0;                    // own row mask (lane<16 valid)
  #pragma unroll
  for (int c = 0; c < 4; ++c){
    int4v cw = cb[c];                             // 4 col-words, conflict-free b128
    #pragma unroll
    for (int q = 0; q < 4; ++q){
      const int k = c*4 + q;
      uint32_t w   = (uint32_t)cw[q];             // PRT[lane>>4][16w+k]
      uint32_t aij = (w >> sh) & 3u;              // A[i][lane]
      uint32_t aji = (rpw >> (2*k)) & 3u;         // A[lane][i]
      uint32_t af  = aij | aji;                   // Af[i][lane] (disjoint)
      unsigned long long bal = __ballot(af != 0u);// full row-i nonzero mask
      mymk = (lane == k) ? bal : mymk;
      int arom_i = (int)((aromBits >> (ibase + k)) & 1ull);   // uniform scalar
      int idx = (int)af + (aromsel & (0 - arom_i));
      float bw = bw2[idx];
      // de_s computed arithmetically (no LDS table):
      float eai = __int_as_float(__builtin_amdgcn_readlane(__float_as_int(ea), ibase + k));
      float de  = ea - eai;                       // e_at[j=lane] - e_at[i]  (ref sign)
      float t   = exp2f(beta * log2f(fabsf(de))); // |de|^beta; de=0 -> 0
      float ds  = __int_as_float(__float_as_int(t) |
                                 (__float_as_int(de) & 0x80000000u));
      tv[k] = ds;
      ei = fmaf(bw, ds, ei);
    }
  }
  if (lane < 16) MK[ibase + lane] = mymk;
  __syncthreads();

  // ---- pass B: one3 term via b64 preload + readlane (no per-k LDS) ----
  const unsigned long long mkj = MK[lane];               // own row mask
  const unsigned long long mkv = MK[ibase + (lane & 15)];// wave's 16 masks
  const int vlo = (int)(uint32_t)mkv;
  const int vhi = (int)(uint32_t)(mkv >> 32);
  #pragma unroll
  for (int k = 0; k < 16; ++k){
    uint32_t milo = (uint32_t)__builtin_amdgcn_readlane(vlo, k);
    uint32_t mihi = (uint32_t)__builtin_amdgcn_readlane(vhi, k);
    unsigned long long mki =
        (((unsigned long long)mihi) << 32) | milo;       // MK[ibase+k]
    float add = ((mki & mkj) != 0ull) ? alpha4 : 0.f;
    ei = fmaf(add, tv[k], ei);
  }
  EI[wid*NA + lane] = ei;
  __syncthreads();

  // ---- epilogue: wave 0 combines partials, solves, writes ----
  if (wid == 0){
    float eif = EI[lane] + EI[NA + lane] + EI[2*NA + lane] + EI[3*NA + lane];
    float esv = eif * sinv;
    float sv  = sinv;
    #pragma unroll
    for (int off = 32; off; off >>= 1){
      esv += __shfl_xor(esv, off);
      sv  += __shfl_xor(sv,  off);
    }
    const float lam = (Q[m] + esv) / sv;
    out[(size_t)m*NA + lane] = sinv * (lam - eif);
  }
}

extern "C" void kernel_launch(void* const* d_in, const int* in_sizes, int n_in,
                              void* d_out, int out_size, void* d_ws, size_t ws_size,
                              hipStream_t stream)
{
  const int*   atoms = (const int*)  d_in[0];
  const float* A     = (const float*)d_in[1];
  const float* Q     = (const float*)d_in[2];
  const float* e     = (const float*)d_in[3];
  const float* s     = (const float*)d_in[4];
  const float* alpha = (const float*)d_in[5];
  const float* beta  = (const float*)d_in[6];
  float* out = (float*)d_out;

  const int B = in_sizes[2];                 // Q: one entry per molecule
  hipLaunchKernelGGL(vcharge_kernel, dim3(B), dim3(256), 0, stream,
                     atoms, A, Q, e, s, alpha, beta, out);
}

// Round 12
// 25.097 us; speedup vs baseline: 1.1577x; 1.0849x over previous
//
#include <hip/hip_runtime.h>
#include <cstdint>

#define NTYPES 39
#define NA 64
#define TABN (NTYPES*NTYPES)   // 1521

typedef float float4v __attribute__((ext_vector_type(4)));
typedef int   int4v   __attribute__((ext_vector_type(4)));

__global__ __launch_bounds__(256) void vcharge_kernel(
    const int*   __restrict__ atoms,
    const float* __restrict__ A,
    const float* __restrict__ Q,
    const float* __restrict__ e,
    const float* __restrict__ s,
    const float* __restrict__ alpha,
    const float* __restrict__ beta_p,
    float*       __restrict__ out)
{
  __shared__ float    tab[TABN];    // signed |e_b - e_a|^beta by (a=ty_i, b=ty_j)
  __shared__ float    bw2[8];       // bond weight by (af | aromboth<<2)
  __shared__ uint32_t PRT[4*68];    // 2-bit cols, [word][row], stride 68
  __shared__ uint32_t CN[4*NA];     // per-wave column-mask slices (16 bits each)
  __shared__ float    EI[4*NA];     // per-wave partial e_i

  const int tid  = threadIdx.x;
  const int wid  = tid >> 6;
  const int lane = tid & 63;
  const int m    = blockIdx.x;

  // ---- in-kernel table fill (6 exp2/log2 chains per thread, amortized) ----
  const float beta = beta_p[0];
  for (int k = tid; k < TABN; k += 256){
    int a = k / NTYPES;
    int b = k - a*NTYPES;
    float d = e[b] - e[a];
    float t = exp2f(beta * log2f(fabsf(d)));   // d==0: log2->-inf, exp2->0
    tab[k] = (d > 0.f) ? t : ((d < 0.f) ? -t : 0.f);
  }
  if (tid < 8){
    float a0 = alpha[0], a1 = alpha[1], a2 = alpha[2], a3 = alpha[3];
    int af = tid & 3;
    float bv = (af == 1) ? a0 : ((af == 2) ? a1 : ((af == 3) ? a2 : 0.f));
    if ((tid & 4) && af != 0) bv += a3;   // marom needs Af>0 and both aromatic
    bw2[tid] = bv;
  }

  // ---- phase 1: LANE-CONTIGUOUS loads (1KiB/instr), byte-pack into PRT ----
  // thread t owns col-quad c4 = t&15 (word c4>>2, byte c4&3) for rows t>>4 + 16l
  {
    const float4v* A4 = (const float4v*)(A + (size_t)m * (NA*NA));
    float4v v0 = A4[tid];
    float4v v1 = A4[tid + 256];
    float4v v2 = A4[tid + 512];
    float4v v3 = A4[tid + 768];
    uint8_t* PB = (uint8_t*)PRT;
    const int c4   = tid & 15;
    const int r0   = tid >> 4;
    const int base = ((c4 >> 2)*68)*4 + (c4 & 3);   // byte offset of (word, row 0)
    float f0 = fmaf(fmaf(fmaf(v0[3],4.f,v0[2]),4.f,v0[1]),4.f,v0[0]);
    float f1 = fmaf(fmaf(fmaf(v1[3],4.f,v1[2]),4.f,v1[1]),4.f,v1[0]);
    float f2 = fmaf(fmaf(fmaf(v2[3],4.f,v2[2]),4.f,v2[1]),4.f,v2[0]);
    float f3 = fmaf(fmaf(fmaf(v3[3],4.f,v3[2]),4.f,v3[1]),4.f,v3[0]);
    PB[base + (r0      )*4] = (uint8_t)(int)f0;     // exact: values 0..255
    PB[base + (r0 + 16 )*4] = (uint8_t)(int)f1;
    PB[base + (r0 + 32 )*4] = (uint8_t)(int)f2;
    PB[base + (r0 + 48 )*4] = (uint8_t)(int)f3;
  }

  // per-lane atom constants (overlap with phase 1)
  const int ty = atoms[m*NA + lane];
  const float sinv = 1.0f / s[ty];
  const float alpha4 = alpha[4];
  const uint64_t AROM = (1ull<<6)|(1ull<<10)|(1ull<<19)|(1ull<<20)|(1ull<<21)|(1ull<<22)|(1ull<<32);
  const int aromt = (int)((AROM >> ty) & 1ull);
  const unsigned long long aromBits = __ballot(aromt);  // identical per wave
  const int aromsel = aromt << 2;

  __syncthreads();

  // ---- pass A: af + local column-mask bits + bond-term FMA + tab stash ----
  const int sh  = 2 * (lane & 15);
  const uint32_t rpw = PRT[wid*68 + lane];        // A[lane][16w..16w+16)
  const int4v* cb = (const int4v*)&PRT[(lane >> 4)*68 + wid*16];
  const int ibase = wid * 16;
  float tv[16];                                   // stashed tab values (VGPRs)
  float ei = 0.f;
  uint32_t nz = 0;                                // Af[i][lane]!=0 bits, i=ibase+k
  #pragma unroll
  for (int c = 0; c < 4; ++c){
    int4v cw = cb[c];                             // 4 col-words, conflict-free b128
    #pragma unroll
    for (int q = 0; q < 4; ++q){
      const int k = c*4 + q;
      uint32_t w   = (uint32_t)cw[q];             // PRT[lane>>4][16w+k]
      uint32_t aij = (w >> sh) & 3u;              // A[i][lane]
      uint32_t aji = (rpw >> (2*k)) & 3u;         // A[lane][i]
      uint32_t af  = aij | aji;                   // Af[i][lane] (disjoint)
      nz |= ((af + 3u) >> 2) << k;                // bit k = (af != 0)
      int arom_i = (int)((aromBits >> (ibase + k)) & 1ull);   // uniform scalar
      int idx = (int)af + (aromsel & (0 - arom_i));
      float bw = bw2[idx];
      int tyi = __builtin_amdgcn_readlane(ty, ibase + k);     // uniform
      float t  = tab[tyi*NTYPES + ty];
      tv[k] = t;
      ei = fmaf(bw, t, ei);
    }
  }
  CN[wid*NA + lane] = nz;                         // this wave's 16-bit slice
  __syncthreads();

  // ---- combine slices: full column mask of own atom (== row mask, Af sym) ----
  const uint32_t lo = CN[0*NA + lane] | (CN[1*NA + lane] << 16);
  const uint32_t hi = CN[2*NA + lane] | (CN[3*NA + lane] << 16);
  const unsigned long long mkj = (((unsigned long long)hi) << 32) | lo;
  const int vlo = (int)lo, vhi = (int)hi;

  // ---- pass B: one3 term; mki via readlane of own-register masks ----
  #pragma unroll
  for (int k = 0; k < 16; ++k){
    uint32_t milo = (uint32_t)__builtin_amdgcn_readlane(vlo, ibase + k);
    uint32_t mihi = (uint32_t)__builtin_amdgcn_readlane(vhi, ibase + k);
    unsigned long long mki =
        (((unsigned long long)mihi) << 32) | milo;   // mask of atom i
    float add = ((mki & mkj) != 0ull) ? alpha4 : 0.f;
    ei = fmaf(add, tv[k], ei);
  }
  EI[wid*NA + lane] = ei;
  __syncthreads();

  // ---- epilogue: wave 0 combines partials, solves, writes ----
  if (wid == 0){
    float eif = EI[lane] + EI[NA + lane] + EI[2*NA + lane] + EI[3*NA + lane];
    float esv = eif * sinv;
    float sv  = sinv;
    #pragma unroll
    for (int off = 32; off; off >>= 1){
      esv += __shfl_xor(esv, off);
      sv  += __shfl_xor(sv,  off);
    }
    const float lam = (Q[m] + esv) / sv;
    out[(size_t)m*NA + lane] = sinv * (lam - eif);
  }
}

extern "C" void kernel_launch(void* const* d_in, const int* in_sizes, int n_in,
                              void* d_out, int out_size, void* d_ws, size_t ws_size,
                              hipStream_t stream)
{
  const int*   atoms = (const int*)  d_in[0];
  const float* A     = (const float*)d_in[1];
  const float* Q     = (const float*)d_in[2];
  const float* e     = (const float*)d_in[3];
  const float* s     = (const float*)d_in[4];
  const float* alpha = (const float*)d_in[5];
  const float* beta  = (const float*)d_in[6];
  float* out = (float*)d_out;

  const int B = in_sizes[2];                 // Q: one entry per molecule
  hipLaunchKernelGGL(vcharge_kernel, dim3(B), dim3(256), 0, stream,
                     atoms, A, Q, e, s, alpha, beta, out);
}